// Round 10
// baseline (211.955 us; speedup 1.0000x reference)
//
#include <hip/hip_runtime.h>

#define BB 4
#define NN 16384
#define SS 4096
#define CC 256
#define TLD 132  // gather tile leading dim (words): 128ch + 4 pad, rows 16B-aligned

typedef float f32x4 __attribute__((ext_vector_type(4)));  // for nontemporal builtins

__device__ __forceinline__ bool lexlt(float da, int ia, float db, int ib) {
  // strict (d, idx) lexicographic order — matches jax.lax.top_k tie-break
  return (da < db) || ((da == db) && (ia < ib));
}

// exact np replication: d = qq - 2*dot + kk, left-to-right, no contract
#define DIST(kp) ({                                        \
  float _dot = (qx * (kp).x + qy * (kp).y) + qz * (kp).z;  \
  __builtin_fmaf(_dot, -2.0f, qq) + (kp).w;                \
})

// byte-identical top-3 insert (idempotent when dd >= d2)
#define INSERT(dd, ss) do {                                \
  bool _k2 = (dd) < d2, _k1 = (dd) < d1, _k0 = (dd) < d0;  \
  float _nd2 = __builtin_amdgcn_fmed3f((dd), d1, d2);      \
  float _nd1 = __builtin_amdgcn_fmed3f((dd), d0, d1);      \
  float _nd0 = fminf((dd), d0);                            \
  i2 = _k1 ? i1 : (_k2 ? (ss) : i2);                       \
  i1 = _k0 ? i0 : (_k1 ? (ss) : i1);                       \
  i0 = _k0 ? (ss) : i0;                                    \
  d2 = _nd2; d1 = _nd1; d0 = _nd0;                         \
} while (0)

// ---------------- Kernel A: bundle-gated scan, half-seg split, 32 waves/CU ----------------
// Grid 2048 = b(4) x seg(4) x qgrp(128); 256 thr (4 waves); 8 blocks/CU, 32 waves/CU
// (2x R9 occupancy). Wave wv: qg2 = wv&1 (which 64-query group), half = wv>>1 (which
// 512-candidate half of the staged 1024-seg). Bundle gating as R9 (16-cand bundles,
// branch-free dist block + 16-bit wave-uniform mask + scalar-branch insert sweep),
// but tau frozen per bundle FROM THE START (first bundles have tau=3.4e38 -> all
// open -> seeds top-3; identical behavior to an ungated prefix). After the scan the
// two half-seg waves of each query group merge via the R0-proven 3-step lexlt merge
// (LDS overlay) and the low-half wave writes one 4-slot partial -> gather unchanged.
// Exact: insert body byte-identical; s ascending per wave; low-half s < high-half s
// and lexlt merge preserves the (d, idx) tie-break.
__global__ __launch_bounds__(256, 8) void scan_kernel(
    const float* __restrict__ qg, const float* __restrict__ kg,
    float4* __restrict__ dpart, int4* __restrict__ ipart) {
#pragma clang fp contract(off)
  __shared__ __align__(16) float4 kpts[1024];  // 16 KB
  float* md = (float*)kpts;                    // [2][64][3] floats (1.5 KB), overlaid
  int* mi = (int*)((char*)kpts + 1536);        // [2][64][3] ints   (1.5 KB)

  const int tid = threadIdx.x;
  const int blk = blockIdx.x;
  const int b = blk >> 9;
  const int seg = (blk >> 7) & 3;
  const int n0 = (blk & 127) << 7;  // 128 queries per block
  const int wv = tid >> 6;
  const int lane = tid & 63;
  const int qg2 = wv & 1;   // query group 0/1
  const int half = wv >> 1; // candidate half 0/1
  const int q = n0 + qg2 * 64 + lane;  // this lane's query

  // ---- stage this segment's 1024 points as {x,y,z,kk} ----
  {
    const float* kb = kg + ((long)b * SS + (long)seg * 1024) * 3;
    const float4* src = (const float4*)kb + tid * 3;
    float4 f0 = src[0], f1 = src[1], f2 = src[2];
    float px[4] = {f0.x, f0.w, f1.z, f2.y};
    float py[4] = {f0.y, f1.x, f1.w, f2.z};
    float pz[4] = {f0.z, f1.y, f2.x, f2.w};
#pragma unroll
    for (int m = 0; m < 4; ++m) {
      float kk = (px[m] * px[m] + py[m] * py[m]) + pz[m] * pz[m];  // np order
      kpts[tid * 4 + m] = make_float4(px[m], py[m], pz[m], kk);
    }
  }

  const float* qp = qg + ((long)b * NN + q) * 3;
  float qx = qp[0], qy = qp[1], qz = qp[2];
  float qq = (qx * qx + qy * qy) + qz * qz;  // np sum order
  float d0 = 3.4e38f, d1 = 3.4e38f, d2 = 3.4e38f;
  int i0 = 0, i1 = 0, i2 = 0;
  __syncthreads();

  const int sb = seg * 1024;
  const int cbase = half << 9;  // this wave's 512-candidate window

  // ---- 32 bundles of 16, tau frozen per bundle (first bundles: tau=inf -> open) ----
  for (int bdl = 0; bdl < 32; ++bdl) {
    const int base = cbase + (bdl << 4);
    const float tau = d2;  // per-lane; d2_run <= tau within the bundle
    float dv[16];
    unsigned msk = 0;
#pragma unroll
    for (int sj = 0; sj < 4; ++sj) {  // 4 cands per sub-bundle bounds VGPR pressure
      float4 ka = kpts[base + 4 * sj + 0];
      float4 kb_ = kpts[base + 4 * sj + 1];
      float4 kc = kpts[base + 4 * sj + 2];
      float4 kd = kpts[base + 4 * sj + 3];
      dv[4 * sj + 0] = DIST(ka);
      dv[4 * sj + 1] = DIST(kb_);
      dv[4 * sj + 2] = DIST(kc);
      dv[4 * sj + 3] = DIST(kd);
    }
#pragma unroll
    for (int j = 0; j < 16; ++j) msk |= (__any(dv[j] < tau) ? 1u : 0u) << j;
    if (msk) {
#pragma unroll
      for (int j = 0; j < 16; ++j) {
        if (msk & (1u << j)) INSERT(dv[j], sb + base + j);
      }
    }
  }

  // ---- intra-block merge of the two half-seg waves (R0-proven 3-step network) ----
  __syncthreads();  // all kpts reads done; md/mi overlay kpts
  if (half == 1) {
    int basei = (qg2 * 64 + lane) * 3;
    md[basei + 0] = d0; md[basei + 1] = d1; md[basei + 2] = d2;
    mi[basei + 0] = i0; mi[basei + 1] = i1; mi[basei + 2] = i2;
  }
  __syncthreads();
  if (half == 0) {
    int basei = (qg2 * 64 + lane) * 3;
    float E0 = md[basei + 0], E1 = md[basei + 1], E2 = md[basei + 2];
    int F0 = mi[basei + 0], F1 = mi[basei + 1], F2 = mi[basei + 2];
    float A0 = d0, A1 = d1, A2 = d2;
    int B0 = i0, B1 = i1, B2 = i2;
    bool t = lexlt(E0, F0, A0, B0);
    float r0 = t ? E0 : A0; int s0 = t ? F0 : B0;
    float nA0 = t ? A0 : A1, nA1 = t ? A1 : A2;
    int nB0 = t ? B0 : B1, nB1 = t ? B1 : B2;
    float nE0 = t ? E1 : E0, nE1 = t ? E2 : E1;
    int nF0 = t ? F1 : F0, nF1 = t ? F2 : F1;
    bool u = lexlt(nE0, nF0, nA0, nB0);
    float r1 = u ? nE0 : nA0; int s1 = u ? nF0 : nB0;
    float mA0 = u ? nA0 : nA1; int mB0 = u ? nB0 : nB1;
    float mE0 = u ? nE1 : nE0; int mF0 = u ? nF1 : nF0;
    bool w = lexlt(mE0, mF0, mA0, mB0);
    float r2 = w ? mE0 : mA0; int s2 = w ? mF0 : mB0;
    long gid = (long)b * NN + q;
    dpart[gid * 4 + seg] = make_float4(r0, r1, r2, 0.0f);
    ipart[gid * 4 + seg] = make_int4(s0, s1, s2, 0);
  }
}

// ---------------- Kernel B: merge partials + gather + transpose ----------------
// Verbatim R3 (v3b): XCD-affinity decomposition, measured ~21 us. Grid 2048;
// round-robin dispatch -> XCD = bid&7; each XCD owns one (batch, channel-half):
// per-XCD V working set 2 MB < 4 MB L2. NT stores keep writes from evicting V.
__global__ __launch_bounds__(256, 4) void gather_kernel(
    const float* __restrict__ vg, const float4* __restrict__ dpart,
    const int4* __restrict__ ipart, float* __restrict__ outg) {
#pragma clang fp contract(off)
  __shared__ __align__(16) float tile[64 * TLD];  // 33.8 KB
  __shared__ float sw[64][3];
  __shared__ int si[64][3];

  const int tid = threadIdx.x;
  const int bid = blockIdx.x;
  const int xcd = bid & 7;     // dispatch round-robin: block -> XCD
  const int b = xcd >> 1;      // 2 XCDs per batch
  const int chunk = xcd & 1;   // which 128-channel half this XCD handles
  const int nblk = bid >> 3;   // 0..255
  const int n0 = nblk << 6;    // 64 queries per block

  if (tid < 64) {
    long gid = (long)b * NN + n0 + tid;
    float D0 = 3.4e38f, D1 = 3.4e38f, D2 = 3.4e38f;
    int I0 = -1, I1 = -1, I2 = -1;
#pragma unroll
    for (int seg = 0; seg < 4; ++seg) {
      float4 dv = dpart[gid * 4 + seg];
      int4 iv = ipart[gid * 4 + seg];
      float ds_[3] = {dv.x, dv.y, dv.z};
      int is_[3] = {iv.x, iv.y, iv.z};
      for (int r = 0; r < 3; ++r) {
        float d = ds_[r];
        int s = is_[r];
        if (lexlt(d, s, D2, I2)) {
          if (lexlt(d, s, D1, I1)) {
            D2 = D1; I2 = I1;
            if (lexlt(d, s, D0, I0)) { D1 = D0; I1 = I0; D0 = d; I0 = s; }
            else { D1 = d; I1 = s; }
          } else { D2 = d; I2 = s; }
        }
      }
    }
    // weights exactly as ref: recip = 1/(d+1e-8) on ascending dists, then normalize
    float r0 = 1.0f / (D0 + 1e-8f);
    float r1 = 1.0f / (D1 + 1e-8f);
    float r2 = 1.0f / (D2 + 1e-8f);
    float rs = (r0 + r1) + r2;
    sw[tid][0] = r0 / rs; sw[tid][1] = r1 / rs; sw[tid][2] = r2 / rs;
    si[tid][0] = I0; si[tid][1] = I1; si[tid][2] = I2;
  }
  __syncthreads();

  const int wv = tid >> 6;      // wave id 0..3 -> owns queries wv*16 .. wv*16+15
  const int lane = tid & 63;
  const int qh = lane >> 5;     // half-wave: which of 2 queries this iteration
  const int slot = lane & 31;   // f4 slot within the 128-channel half
  const float* vb = vg + (long)b * SS * CC + chunk * 128;

#pragma unroll 4
  for (int it = 0; it < 8; ++it) {
    int qs = wv * 16 + it * 2 + qh;
    float w0 = sw[qs][0], w1 = sw[qs][1], w2 = sw[qs][2];
    const float4* r0p = (const float4*)(vb + (long)si[qs][0] * CC);
    const float4* r1p = (const float4*)(vb + (long)si[qs][1] * CC);
    const float4* r2p = (const float4*)(vb + (long)si[qs][2] * CC);
    float4 a0 = r0p[slot], a1 = r1p[slot], a2 = r2p[slot];
    float4 acc;
    acc.x = (w0 * a0.x + w1 * a1.x) + w2 * a2.x;
    acc.y = (w0 * a0.y + w1 * a1.y) + w2 * a2.y;
    acc.z = (w0 * a0.z + w1 * a1.z) + w2 * a2.z;
    acc.w = (w0 * a0.w + w1 * a1.w) + w2 * a2.w;
    *(float4*)&tile[qs * TLD + slot * 4] = acc;
  }
  __syncthreads();

  // store: 128 channels x 64 n; each thread assembles float4 along n (non-temporal)
  {
    const int nf = tid & 15;   // f4 group along n
    const int cb0 = tid >> 4;  // channel base 0..15
    const int q0 = nf << 2;    // first of 4 consecutive queries (n)
#pragma unroll 2
    for (int it = 0; it < 8; ++it) {
      int cl = cb0 + it * 16;           // channel within half 0..127
      int cch = (chunk << 7) + cl;      // global channel
      f32x4 val;
      val.x = tile[(q0 + 0) * TLD + cl];
      val.y = tile[(q0 + 1) * TLD + cl];
      val.z = tile[(q0 + 2) * TLD + cl];
      val.w = tile[(q0 + 3) * TLD + cl];
      __builtin_nontemporal_store(
          val, (f32x4*)&outg[((long)(b * CC + cch)) * NN + n0 + q0]);
    }
  }
}

extern "C" void kernel_launch(void* const* d_in, const int* in_sizes, int n_in,
                              void* d_out, int out_size, void* d_ws, size_t ws_size,
                              hipStream_t stream) {
  const float* q = (const float*)d_in[0];
  const float* k = (const float*)d_in[1];
  const float* v = (const float*)d_in[2];
  float* out = (float*)d_out;
  float4* dpart = (float4*)d_ws;                                          // 4 MB
  int4* ipart = (int4*)((char*)d_ws + (size_t)BB * NN * 4 * 16);          // 4 MB
  hipLaunchKernelGGL(scan_kernel, dim3(2048), dim3(256), 0, stream, q, k, dpart, ipart);
  hipLaunchKernelGGL(gather_kernel, dim3(2048), dim3(256), 0, stream, v, dpart, ipart, out);
}